// Round 9
// baseline (169.689 us; speedup 1.0000x reference)
//
#include <hip/hip_runtime.h>
#include <hip/hip_bf16.h>

typedef __bf16 bf16_t;
typedef __bf16 bf16x4 __attribute__((ext_vector_type(4)));
typedef __bf16 bf16x8 __attribute__((ext_vector_type(8)));
typedef float f32x4 __attribute__((ext_vector_type(4)));
typedef float f32x8 __attribute__((ext_vector_type(8)));

#define MFMA16(a, b, c) __builtin_amdgcn_mfma_f32_16x16x32_bf16(a, b, c, 0, 0, 0)

#define GLOAD_LDS16(g, l)                                              \
  __builtin_amdgcn_global_load_lds(                                    \
      (const __attribute__((address_space(1))) unsigned int*)(g),      \
      (__attribute__((address_space(3))) unsigned int*)(l), 16, 0, 0)

constexpr int B = 2, T = 2048, C = 1024, H = 16, D = 64;
constexpr int NQKV = 3 * C;   // 3072
constexpr int M = B * T;      // 4096

// Q pre-scaled at QKV time by 1/sqrt(D)*log2(e): attn softmax = bare exp2.
#define QSCALE 0.18033688011112042f

struct TOn  { static constexpr bool value = true;  };
struct TOff { static constexpr bool value = false; };

// ---------------------------------------------------------------------------
// Kernel 0: f32 -> bf16 convert (x, attn_w, proj_w).
// ---------------------------------------------------------------------------
__global__ __launch_bounds__(256) void cvt_kernel(
    const float* __restrict__ s0, bf16_t* __restrict__ d0, int n0,
    const float* __restrict__ s1, bf16_t* __restrict__ d1, int n1,
    const float* __restrict__ s2, bf16_t* __restrict__ d2, int n2)
{
  const float* s; bf16_t* d; int n;
  if (blockIdx.y == 0)      { s = s0; d = d0; n = n0; }
  else if (blockIdx.y == 1) { s = s1; d = d1; n = n1; }
  else                      { s = s2; d = d2; n = n2; }
  const int idx = (blockIdx.x * 256 + threadIdx.x) * 8;
  if (idx >= n) return;
  f32x8 t = *(const f32x8*)(s + idx);
  bf16x8 r;
#pragma unroll
  for (int j = 0; j < 8; ++j) r[j] = (bf16_t)t[j];
  *(bf16x8*)(d + idx) = r;
}

// ---------------------------------------------------------------------------
// GEMM mainloop (dbuf, generalized wave grid WM x WN): BM x BN block tile,
// double-buffered LDS, one barrier per BK=64 iteration, XOR chunk swizzle,
// width-16 global_load_lds.  Wave tile (MI*16) x (NI*16).
// ---------------------------------------------------------------------------
template<int BM, int BN, int MI, int NI, int WM, int WN>
__device__ __forceinline__ void gemm_mainloop_db(
    const bf16_t* __restrict__ A, const bf16_t* __restrict__ Wt,
    const int K, const int m0, const int n0,
    bf16_t* ldsA0, bf16_t* ldsA1, bf16_t* ldsB0, bf16_t* ldsB1,
    f32x4 acc[MI][NI])
{
  const int tid  = threadIdx.x;
  const int wv   = tid >> 6;
  const int lane = tid & 63;
  const int col  = lane & 15;
  const int quad = lane >> 4;
  const int lr8  = lane >> 3;
  const int cpos = lane & 7;
  const int wm = wv / WN, wn = wv % WN;
  constexpr int NW  = WM * WN;
  constexpr int ARW = BM / NW;
  constexpr int AJ  = ARW / 8;
  constexpr int BRW = BN / NW;
  constexpr int BJ  = BRW / 8;

  const bf16_t* ag[AJ]; const bf16_t* bg[BJ];
#pragma unroll
  for (int j = 0; j < AJ; ++j)
    ag[j] = A + (size_t)(m0 + wv * ARW + j * 8 + lr8) * K + (cpos ^ lr8) * 8;
#pragma unroll
  for (int j = 0; j < BJ; ++j)
    bg[j] = Wt + (size_t)(n0 + wv * BRW + j * 8 + lr8) * K + (cpos ^ lr8) * 8;

  const int xa = quad ^ (col & 7);
  const int niter = K / 64;

#pragma unroll
  for (int j = 0; j < AJ; ++j)
    GLOAD_LDS16(ag[j], ldsA0 + (wv * ARW + j * 8) * 64);
#pragma unroll
  for (int j = 0; j < BJ; ++j)
    GLOAD_LDS16(bg[j], ldsB0 + (wv * BRW + j * 8) * 64);

  for (int it = 0; it < niter; ++it) {
    __syncthreads();
    const bf16_t* cA = (it & 1) ? ldsA1 : ldsA0;
    const bf16_t* cB = (it & 1) ? ldsB1 : ldsB0;
    if (it + 1 < niter) {
      bf16_t* nA = (it & 1) ? ldsA0 : ldsA1;
      bf16_t* nB = (it & 1) ? ldsB0 : ldsB1;
      const int off = (it + 1) * 64;
#pragma unroll
      for (int j = 0; j < AJ; ++j)
        GLOAD_LDS16(ag[j] + off, nA + (wv * ARW + j * 8) * 64);
#pragma unroll
      for (int j = 0; j < BJ; ++j)
        GLOAD_LDS16(bg[j] + off, nB + (wv * BRW + j * 8) * 64);
    }
#pragma unroll
    for (int ks = 0; ks < 2; ++ks) {
      const int xk = (xa ^ (ks * 4)) * 8;
      bf16x8 af[MI], bfr[NI];
#pragma unroll
      for (int mi = 0; mi < MI; ++mi)
        af[mi] = *(const bf16x8*)(cA + (wm * (MI * 16) + mi * 16 + col) * 64 + xk);
#pragma unroll
      for (int ni = 0; ni < NI; ++ni)
        bfr[ni] = *(const bf16x8*)(cB + (wn * (NI * 16) + ni * 16 + col) * 64 + xk);
#pragma unroll
      for (int mi = 0; mi < MI; ++mi)
#pragma unroll
        for (int ni = 0; ni < NI; ++ni)
          acc[mi][ni] = MFMA16(af[mi], bfr[ni], acc[mi][ni]);
    }
  }
}

// ---------------------------------------------------------------------------
// Kernel 1: QKV GEMM — 128x128 dbuf, 256 threads (2x2 waves, 64x64 wave
// tile), 64 KB LDS, 2/CU.  1D grid 768, XCD swizzle co-locating same-m-panel
// blocks.  Q pre-scaled by QSCALE.  V: LDS-bounce transpose, sigma
// permutation sigma(t) = (t&15)*4 + ((t>>4)&3).
// ---------------------------------------------------------------------------
__global__ __launch_bounds__(256) void qkv_gemm_kernel(
    const bf16_t* __restrict__ x, const bf16_t* __restrict__ w,
    const float* __restrict__ bias,
    bf16_t* __restrict__ qws, bf16_t* __restrict__ kws, bf16_t* __restrict__ vws)
{
  __shared__ __align__(16) bf16_t ldsA[2][128 * 64];   // 32 KB
  __shared__ __align__(16) bf16_t ldsB[2][128 * 64];   // 32 KB
  const unsigned id = blockIdx.x;
  const unsigned lo = id & 7;
  const unsigned hi = id >> 3;            // 0..95
  const unsigned bx = hi % 24;            // n-block 0..23
  const unsigned by = lo + 8 * (hi / 24); // m-block 0..31
  const int lane = threadIdx.x & 63;
  const int wv   = threadIdx.x >> 6;
  const int col  = lane & 15;
  const int quad = lane >> 4;
  const int wm = wv >> 1, wn = wv & 1;
  const int m0 = by * 128;
  const int n0 = bx * 128;

  f32x4 acc[4][4] = {};
  gemm_mainloop_db<128, 128, 4, 4, 2, 2>(x, w, C, m0, n0,
                                         ldsA[0], ldsA[1], ldsB[0], ldsB[1], acc);

  const int which = n0 >> 10;          // block-uniform: 0=Q, 1=K, 2=V

  if (which == 2) {
    // ---- V path: LDS-bounce transpose (wave tile 64 t x 64 d = one head) --
    __syncthreads();                   // mainloop readers done; reuse ldsA
    bf16_t* vt = &ldsA[0][0] + wv * 4096;   // 8 KB wave-private region

#pragma unroll
    for (int ni = 0; ni < 4; ++ni) {
      const int n = n0 + wn * 64 + ni * 16 + col;
      const float bval = bias[n];
      const int dl = ni * 16 + col;    // 0..63 within wave region
#pragma unroll
      for (int r = 0; r < 4; ++r) {
        bf16x4 pw;
#pragma unroll
        for (int mi = 0; mi < 4; ++mi)
          pw[mi] = (bf16_t)(acc[mi][ni][r] + bval);
        // sigma base = (quad*4+r)*4; chunk k = (quad*4+r)>>1
        const int k = 2 * quad + (r >> 1);
        const int S = dl * 8 + (k ^ (dl & 7));
        *(bf16x4*)(vt + S * 8 + (r & 1) * 4) = pw;
      }
    }

    const int b   = (m0 + wm * 64) >> 11;
    const int t0w = (m0 + wm * 64) & (T - 1);    // 64-aligned
    const int h   = ((n0 + wn * 64) & (C - 1)) >> 6;   // one head per wave
    const size_t bh = (size_t)(b * H + h);
    const int lr8 = lane >> 3;
    const int c8  = lane & 7;
#pragma unroll
    for (int j = 0; j < 8; ++j) {
      const int dl = j * 8 + lr8;                // 0..63
      const int d  = dl;
      bf16x8 row = *(const bf16x8*)(vt + (dl * 8 + (c8 ^ (dl & 7))) * 8);
      *(bf16x8*)(vws + (bh * D + d) * T + t0w + c8 * 8) = row;
    }
  } else {
    // ---- Q/K path ----
#pragma unroll
    for (int ni = 0; ni < 4; ++ni) {
      const int n = n0 + wn * 64 + ni * 16 + col;
      const float bval = bias[n];
      const int c = n & (C - 1);
      const int h = c >> 6;
      const int d = c & 63;
#pragma unroll
      for (int mi = 0; mi < 4; ++mi) {
#pragma unroll
        for (int r = 0; r < 4; ++r) {
          const int m = m0 + wm * 64 + mi * 16 + quad * 4 + r;
          const int b = m >> 11;
          const int t = m & (T - 1);
          const size_t bh = (size_t)(b * H + h);
          if (which == 0)
            qws[(bh * T + t) * D + d] = (bf16_t)((acc[mi][ni][r] + bval) * QSCALE);
          else
            kws[(bh * T + t) * D + d] = (bf16_t)(acc[mi][ni][r] + bval);
        }
      }
    }
  }
}

// ---------------------------------------------------------------------------
// Kernel 2: causal flash attention — round 24: KV-SPLIT for TLP.
// 1024 blocks (was 512): each round-19 pair-block is split into s=0/1.
//   s=0: full LO tile [0..qt_l] + HI tiles [0, h0)      (h0 = 15 - pr)
//   s=1: HI tiles [h0 .. qt_h]  (includes diagonal)
// Balanced ~16/17 tile-units per block.  LO rows (t<1024) written directly;
// HI rows written as f32 partial (o, l) — bare-exp2 softmax has no running
// max, so partials combine exactly in attn_combine_kernel.
// Single shared per-wave P buffer (wave-private; in-order DS pipe makes
// hi->lo reuse safe) -> 40 KB LDS -> 4 blocks/CU (was 2).
// ---------------------------------------------------------------------------
__global__ __launch_bounds__(256) void attn_kernel(
    const bf16_t* __restrict__ qws, const bf16_t* __restrict__ kws,
    const bf16_t* __restrict__ vws, bf16_t* __restrict__ yws,
    float* __restrict__ obuf, float* __restrict__ lbuf)
{
  const unsigned id = blockIdx.x;          // [2:0]=bh_lo [6:3]=pr [7]=s [9:8]=bh_hi
  const int bh = (id & 7) + 8 * (id >> 8);
  const int pr = (id >> 3) & 15;
  const int s  = (id >> 7) & 1;
  const int tid  = threadIdx.x;
  const int wv   = tid >> 6;
  const int lane = tid & 63;
  const int col  = lane & 15;
  const int quad = lane >> 4;

  const bf16_t* Q  = qws + (size_t)bh * T * D;
  const bf16_t* K  = kws + (size_t)bh * T * D;
  const bf16_t* Vt = vws + (size_t)bh * D * T;

  __shared__ __align__(16) bf16_t ldsK[2][64 * 64];      // 16 KB
  __shared__ __align__(16) bf16_t ldsV[2][64 * 64];      // 16 KB
  __shared__ __align__(16) bf16_t ldsP_s[4][16 * 64];    // 8 KB (shared hi/lo)
  bf16_t* ldsPw = ldsP_s[wv];

  const int xs   = col & 7;
  const int cxq  = (quad ^ xs) * 8;
  const int lr8  = lane >> 3;
  const int ksrc = (lane & 7) ^ lr8;
  const int pxor = (quad & 1) * 4;
  const int b = bh >> 4;
  const int h = bh & 15;

  const int qt_h = 31 - pr, qt_l = pr;
  const int h0   = 15 - pr;                // hi-range split point
  const int twh = qt_h * 64 + 16 * wv, twl = qt_l * 64 + 16 * wv;

  bf16x8 qfh0 = *(const bf16x8*)(Q + (size_t)(twh + col) * D + quad * 8);
  bf16x8 qfh1 = *(const bf16x8*)(Q + (size_t)(twh + col) * D + 32 + quad * 8);
  bf16x8 qfl0 = *(const bf16x8*)(Q + (size_t)(twl + col) * D + quad * 8);
  bf16x8 qfl1 = *(const bf16x8*)(Q + (size_t)(twl + col) * D + 32 + quad * 8);

  f32x4 oh[4] = {}, ol[4] = {};
  f32x4 lph = {}, lpl = {};

  auto stage = [&](int it) {
    const int sn = it * 64;
    bf16_t* dK = ldsK[it & 1];
    bf16_t* dV = ldsV[it & 1];
#pragma unroll
    for (int j = 0; j < 2; ++j) {
      GLOAD_LDS16(K + (size_t)(sn + 16 * wv + j * 8 + lr8) * D + ksrc * 8,
                  dK + (16 * wv + j * 8) * 64);
      GLOAD_LDS16(Vt + (size_t)(16 * wv + j * 8 + lr8) * T + sn + ksrc * 8,
                  dV + (16 * wv + j * 8) * 64);
    }
  };

  // One K/V tile vs hi (HI) and/or lo (LO) q-tiles.  K fragments shared.
  // Single P buffer: SM/PV hi fully precede SM/PV lo (wave-private region).
  auto body = [&](auto HIC, auto LOC, const bf16_t* bK, const bf16_t* bV,
                  int s0, bool hdiag, bool ldiag) {
    constexpr bool HI = decltype(HIC)::value;
    constexpr bool LO = decltype(LOC)::value;
    f32x4 sch[4], scl[4];
    __builtin_amdgcn_s_setprio(1);
#pragma unroll
    for (int kb = 0; kb < 4; ++kb) {
      const bf16_t* kr = bK + (kb * 16 + col) * 64;
      bf16x8 kf0 = *(const bf16x8*)(kr + cxq);
      bf16x8 kf1 = *(const bf16x8*)(kr + (cxq ^ 32));
      if constexpr (HI) {
        f32x4 a = {};
        a = MFMA16(qfh0, kf0, a);
        a = MFMA16(qfh1, kf1, a);
        sch[kb] = a;
      }
      if constexpr (LO) {
        f32x4 c = {};
        c = MFMA16(qfl0, kf0, c);
        c = MFMA16(qfl1, kf1, c);
        scl[kb] = c;
      }
    }
    __builtin_amdgcn_s_setprio(0);
    if constexpr (HI) {
#pragma unroll
      for (int r = 0; r < 4; ++r) {
        const int poff = (quad * 4 + r) * 64 +
                         (((col >> 1) ^ (pxor + r)) * 8) + (col & 1) * 4;
        bf16x4 pw;
#pragma unroll
        for (int kb = 0; kb < 4; ++kb) {
          float p = __builtin_amdgcn_exp2f(sch[kb][r]);
          if (hdiag && (s0 + kb * 16 + col > twh + quad * 4 + r)) p = 0.0f;
          lph[r] += p;
          pw[kb] = (bf16_t)p;
        }
        *(bf16x4*)(ldsPw + poff) = pw;
      }
      __builtin_amdgcn_s_setprio(1);
#pragma unroll
      for (int ks = 0; ks < 2; ++ks) {
        const int xk = cxq ^ (ks * 32);
        bf16x8 pa = *(const bf16x8*)(ldsPw + col * 64 + xk);
#pragma unroll
        for (int ni = 0; ni < 4; ++ni) {
          bf16x8 vf = *(const bf16x8*)(bV + (ni * 16 + col) * 64 + xk);
          oh[ni] = MFMA16(pa, vf, oh[ni]);
        }
      }
      __builtin_amdgcn_s_setprio(0);
    }
    if constexpr (LO) {
#pragma unroll
      for (int r = 0; r < 4; ++r) {
        const int poff = (quad * 4 + r) * 64 +
                         (((col >> 1) ^ (pxor + r)) * 8) + (col & 1) * 4;
        bf16x4 pw;
#pragma unroll
        for (int kb = 0; kb < 4; ++kb) {
          float p = __builtin_amdgcn_exp2f(scl[kb][r]);
          if (ldiag && (s0 + kb * 16 + col > twl + quad * 4 + r)) p = 0.0f;
          lpl[r] += p;
          pw[kb] = (bf16_t)p;
        }
        *(bf16x4*)(ldsPw + poff) = pw;
      }
      __builtin_amdgcn_s_setprio(1);
#pragma unroll
      for (int ks = 0; ks < 2; ++ks) {
        const int xk = cxq ^ (ks * 32);
        bf16x8 pa = *(const bf16x8*)(ldsPw + col * 64 + xk);
#pragma unroll
        for (int ni = 0; ni < 4; ++ni) {
          bf16x8 vf = *(const bf16x8*)(bV + (ni * 16 + col) * 64 + xk);
          ol[ni] = MFMA16(pa, vf, ol[ni]);
        }
      }
      __builtin_amdgcn_s_setprio(0);
    }
  };

  if (s == 0) {
    const int stmax = (qt_l > h0 - 1) ? qt_l : (h0 - 1);
    stage(0);
    int it = 0;
    const int nBoth = (h0 < qt_l + 1) ? h0 : (qt_l + 1);
    const bool bothDiag = (qt_l < h0);
    for (; it < nBoth - (bothDiag ? 1 : 0); ++it) {
      __syncthreads();
      if (it + 1 <= stmax) stage(it + 1);
      body(TOn{}, TOn{}, ldsK[it & 1], ldsV[it & 1], it * 64, false, false);
    }
    if (bothDiag) {                      // it == qt_l
      __syncthreads();
      if (it + 1 <= stmax) stage(it + 1);
      body(TOn{}, TOn{}, ldsK[it & 1], ldsV[it & 1], it * 64, false, true);
      ++it;
      for (; it < h0; ++it) {            // hi-only tail
        __syncthreads();
        if (it + 1 <= stmax) stage(it + 1);
        body(TOn{}, TOff{}, ldsK[it & 1], ldsV[it & 1], it * 64, false, false);
      }
    } else {                             // lo-only tail [it, qt_l], diag last
      for (; it < qt_l; ++it) {
        __syncthreads();
        if (it + 1 <= stmax) stage(it + 1);
        body(TOff{}, TOn{}, ldsK[it & 1], ldsV[it & 1], it * 64, false, false);
      }
      __syncthreads();
      body(TOff{}, TOn{}, ldsK[it & 1], ldsV[it & 1], it * 64, false, true);
    }
  } else {
    stage(h0);
    int it = h0;
    for (; it < qt_h; ++it) {
      __syncthreads();
      stage(it + 1);
      body(TOn{}, TOff{}, ldsK[it & 1], ldsV[it & 1], it * 64, false, false);
    }
    __syncthreads();
    body(TOn{}, TOff{}, ldsK[it & 1], ldsV[it & 1], it * 64, true, false);
  }

  // ---- hi epilogue: write f32 partials (all blocks; zeros if no hi work) --
  {
    float* ob = obuf + (size_t)s * (B * H * 1024 * D);
    float* lb = lbuf + s * (B * H * 1024);
    const int orow = bh * 1024;
#pragma unroll
    for (int r = 0; r < 4; ++r) {
      float lh = lph[r];
#pragma unroll
      for (int off = 1; off < 16; off <<= 1) lh += __shfl_xor(lh, off);
      const int tt = twh + quad * 4 + r - 1024;     // >= 0 always
      if ((lane & 15) == 0) lb[orow + tt] = lh;
#pragma unroll
      for (int ni = 0; ni < 4; ++ni)
        ob[(size_t)(orow + tt) * D + ni * 16 + col] = oh[ni][r];
    }
  }
  // ---- lo epilogue (s==0 only): normalize + write y directly ----
  if (s == 0) {
#pragma unroll
    for (int r = 0; r < 4; ++r) {
      float l1 = lpl[r];
#pragma unroll
      for (int off = 1; off < 16; off <<= 1) l1 += __shfl_xor(l1, off);
      const float rl1 = 1.0f / l1;
      const int tl = twl + quad * 4 + r;
#pragma unroll
      for (int ni = 0; ni < 4; ++ni) {
        const int d = ni * 16 + col;
        yws[((size_t)(b * T + tl)) * C + h * D + d] = (bf16_t)(ol[ni][r] * rl1);
      }
    }
  }
}

// ---------------------------------------------------------------------------
// Kernel 2b: combine hi-row partials: y = (o0+o1)/(l0+l1), rows t>=1024.
// 2M elements, 8/thread, 1024 blocks.
// ---------------------------------------------------------------------------
__global__ __launch_bounds__(256) void attn_combine_kernel(
    const float* __restrict__ obuf, const float* __restrict__ lbuf,
    bf16_t* __restrict__ yws)
{
  constexpr int NO = B * H * 1024 * D;   // 2M elems per s
  constexpr int NL = B * H * 1024;
  const int i8 = (blockIdx.x * 256 + threadIdx.x) * 8;
  const int row = i8 >> 6;               // bh*1024 + tt
  const int bh = row >> 10, tt = row & 1023;
  const float rl = 1.0f / (lbuf[row] + lbuf[NL + row]);
  f32x8 a = *(const f32x8*)(obuf + i8);
  f32x8 c = *(const f32x8*)(obuf + NO + i8);
  bf16x8 yv;
#pragma unroll
  for (int j = 0; j < 8; ++j) yv[j] = (bf16_t)((a[j] + c[j]) * rl);
  const int b = bh >> 4, h = bh & 15;
  *(bf16x8*)(yws + ((size_t)(b * T + 1024 + tt)) * C + h * D + (i8 & 63)) = yv;
}

// ---------------------------------------------------------------------------
// Kernel 3: output projection — 128x64 dbuf (48 KB LDS, 512 blocks = 3/CU,
// 16 MFMA/wave/iter), f32 output.  1D grid with XCD co-location.
// ---------------------------------------------------------------------------
__global__ __launch_bounds__(256) void proj_gemm_kernel(
    const bf16_t* __restrict__ y, const bf16_t* __restrict__ w,
    const float* __restrict__ bias, float* __restrict__ out)
{
  __shared__ __align__(16) bf16_t ldsA[2][128 * 64];
  __shared__ __align__(16) bf16_t ldsB[2][64 * 64];
  const unsigned id = blockIdx.x;
  const unsigned lo = id & 7;
  const unsigned hi = id >> 3;            // 0..63
  const unsigned bx = hi & 15;            // n-block 0..15
  const unsigned by = lo + 8 * (hi >> 4); // m-block 0..31
  const int lane = threadIdx.x & 63;
  const int wv   = threadIdx.x >> 6;
  const int col  = lane & 15;
  const int quad = lane >> 4;
  const int wm = wv >> 1, wn = wv & 1;
  const int m0 = by * 128;
  const int n0 = bx * 64;

  f32x4 acc[4][2] = {};
  gemm_mainloop_db<128, 64, 4, 2, 2, 2>(y, w, C, m0, n0,
                                        ldsA[0], ldsA[1], ldsB[0], ldsB[1], acc);

#pragma unroll
  for (int ni = 0; ni < 2; ++ni) {
    const int n = n0 + wn * 32 + ni * 16 + col;
    const float bval = bias[n];
#pragma unroll
    for (int mi = 0; mi < 4; ++mi) {
#pragma unroll
      for (int r = 0; r < 4; ++r) {
        const int m = m0 + wm * 64 + mi * 16 + quad * 4 + r;
        out[(size_t)m * C + n] = acc[mi][ni][r] + bval;
      }
    }
  }
}

// ---------------------------------------------------------------------------
extern "C" void kernel_launch(void* const* d_in, const int* in_sizes, int n_in,
                              void* d_out, int out_size, void* d_ws, size_t ws_size,
                              hipStream_t stream) {
  const float* x      = (const float*)d_in[0];
  const float* attn_w = (const float*)d_in[1];
  const float* attn_b = (const float*)d_in[2];
  const float* proj_w = (const float*)d_in[3];
  const float* proj_b = (const float*)d_in[4];
  float* out = (float*)d_out;

  const size_t E = (size_t)B * H * T * D;   // 4,194,304
  char* ws = (char*)d_ws;
  bf16_t* qws = (bf16_t*)(ws);
  bf16_t* kws = (bf16_t*)(ws + 2 * E);
  bf16_t* vws = (bf16_t*)(ws + 4 * E);
  bf16_t* yws = (bf16_t*)(ws + 6 * E);
  bf16_t* xb  = (bf16_t*)(ws + 8 * E);
  bf16_t* awb = (bf16_t*)(ws + 10 * E);
  bf16_t* pwb = (bf16_t*)(ws + 11 * E + E / 2);
  float*  obuf = (float*)(ws + 12 * E);     // 2 x 2M f32 = 16 MB
  float*  lbuf = (float*)(ws + 16 * E);     // 2 x 32K f32 = 256 KB

  const int NX = M * C, NAW = NQKV * C, NPW = C * C;
  cvt_kernel<<<dim3(NX / 2048, 3), 256, 0, stream>>>(
      x, xb, NX, attn_w, awb, NAW, proj_w, pwb, NPW);
  qkv_gemm_kernel<<<768, 256, 0, stream>>>(xb, awb, attn_b, qws, kws, vws);
  attn_kernel<<<1024, 256, 0, stream>>>(qws, kws, vws, yws, obuf, lbuf);
  attn_combine_kernel<<<(B * H * 1024 * D) / 2048, 256, 0, stream>>>(
      obuf, lbuf, yws);
  proj_gemm_kernel<<<512, 256, 0, stream>>>(yws, pwb, proj_b, out);
}

// Round 10
// 169.171 us; speedup vs baseline: 1.0031x; 1.0031x over previous
//
#include <hip/hip_runtime.h>
#include <hip/hip_bf16.h>

typedef __bf16 bf16_t;
typedef __bf16 bf16x4 __attribute__((ext_vector_type(4)));
typedef __bf16 bf16x8 __attribute__((ext_vector_type(8)));
typedef float f32x4 __attribute__((ext_vector_type(4)));
typedef float f32x8 __attribute__((ext_vector_type(8)));

#define MFMA16(a, b, c) __builtin_amdgcn_mfma_f32_16x16x32_bf16(a, b, c, 0, 0, 0)

#define GLOAD_LDS16(g, l)                                              \
  __builtin_amdgcn_global_load_lds(                                    \
      (const __attribute__((address_space(1))) unsigned int*)(g),      \
      (__attribute__((address_space(3))) unsigned int*)(l), 16, 0, 0)

constexpr int B = 2, T = 2048, C = 1024, H = 16, D = 64;
constexpr int NQKV = 3 * C;   // 3072
constexpr int M = B * T;      // 4096

// Q pre-scaled at QKV time by 1/sqrt(D)*log2(e): attn softmax = bare exp2.
#define QSCALE 0.18033688011112042f

struct LoOn  { static constexpr bool value = true;  };
struct LoOff { static constexpr bool value = false; };

// ---------------------------------------------------------------------------
// Kernel 0: f32 -> bf16 convert (x, attn_w, proj_w).  Exact 1D grid:
// 2048 blocks (x) + 1536 (attn_w) + 512 (proj_w) = 4096, no dead blocks.
// ---------------------------------------------------------------------------
__global__ __launch_bounds__(256) void cvt_kernel(
    const float* __restrict__ s0, bf16_t* __restrict__ d0,
    const float* __restrict__ s1, bf16_t* __restrict__ d1,
    const float* __restrict__ s2, bf16_t* __restrict__ d2)
{
  const int blk = blockIdx.x;
  const float* s; bf16_t* d; int base;
  if (blk < 2048)      { s = s0; d = d0; base = blk; }
  else if (blk < 3584) { s = s1; d = d1; base = blk - 2048; }
  else                 { s = s2; d = d2; base = blk - 3584; }
  const int idx = (base * 256 + threadIdx.x) * 8;
  f32x8 t = *(const f32x8*)(s + idx);
  bf16x8 r;
#pragma unroll
  for (int j = 0; j < 8; ++j) r[j] = (bf16_t)t[j];
  *(bf16x8*)(d + idx) = r;
}

// ---------------------------------------------------------------------------
// GEMM mainloop (dbuf): BM x BN block tile, double-buffered LDS, one barrier
// per BK=64 iteration, XOR chunk swizzle, width-16 global_load_lds.
// 4 waves as 2x2; wave tile (MI*16) x (NI*16).
// ---------------------------------------------------------------------------
template<int BM, int BN, int MI, int NI>
__device__ __forceinline__ void gemm_mainloop_db(
    const bf16_t* __restrict__ A, const bf16_t* __restrict__ Wt,
    const int K, const int m0, const int n0,
    bf16_t* ldsA0, bf16_t* ldsA1, bf16_t* ldsB0, bf16_t* ldsB1,
    f32x4 acc[MI][NI])
{
  const int tid  = threadIdx.x;
  const int wv   = tid >> 6;
  const int lane = tid & 63;
  const int col  = lane & 15;
  const int quad = lane >> 4;
  const int lr8  = lane >> 3;
  const int cpos = lane & 7;
  const int wm = wv >> 1, wn = wv & 1;
  constexpr int AJ = BM / 32;
  constexpr int ARW = BM / 4;
  constexpr int BJ = BN / 32;
  constexpr int BRW = BN / 4;

  const bf16_t* ag[AJ]; const bf16_t* bg[BJ];
#pragma unroll
  for (int j = 0; j < AJ; ++j)
    ag[j] = A + (size_t)(m0 + wv * ARW + j * 8 + lr8) * K + (cpos ^ lr8) * 8;
#pragma unroll
  for (int j = 0; j < BJ; ++j)
    bg[j] = Wt + (size_t)(n0 + wv * BRW + j * 8 + lr8) * K + (cpos ^ lr8) * 8;

  const int xa = quad ^ (col & 7);
  const int niter = K / 64;

#pragma unroll
  for (int j = 0; j < AJ; ++j)
    GLOAD_LDS16(ag[j], ldsA0 + (wv * ARW + j * 8) * 64);
#pragma unroll
  for (int j = 0; j < BJ; ++j)
    GLOAD_LDS16(bg[j], ldsB0 + (wv * BRW + j * 8) * 64);

  for (int it = 0; it < niter; ++it) {
    __syncthreads();
    const bf16_t* cA = (it & 1) ? ldsA1 : ldsA0;
    const bf16_t* cB = (it & 1) ? ldsB1 : ldsB0;
    if (it + 1 < niter) {
      bf16_t* nA = (it & 1) ? ldsA0 : ldsA1;
      bf16_t* nB = (it & 1) ? ldsB0 : ldsB1;
      const int off = (it + 1) * 64;
#pragma unroll
      for (int j = 0; j < AJ; ++j)
        GLOAD_LDS16(ag[j] + off, nA + (wv * ARW + j * 8) * 64);
#pragma unroll
      for (int j = 0; j < BJ; ++j)
        GLOAD_LDS16(bg[j] + off, nB + (wv * BRW + j * 8) * 64);
    }
#pragma unroll
    for (int ks = 0; ks < 2; ++ks) {
      const int xk = (xa ^ (ks * 4)) * 8;
      bf16x8 af[MI], bfr[NI];
#pragma unroll
      for (int mi = 0; mi < MI; ++mi)
        af[mi] = *(const bf16x8*)(cA + (wm * (MI * 16) + mi * 16 + col) * 64 + xk);
#pragma unroll
      for (int ni = 0; ni < NI; ++ni)
        bfr[ni] = *(const bf16x8*)(cB + (wn * (NI * 16) + ni * 16 + col) * 64 + xk);
#pragma unroll
      for (int mi = 0; mi < MI; ++mi)
#pragma unroll
        for (int ni = 0; ni < NI; ++ni)
          acc[mi][ni] = MFMA16(af[mi], bfr[ni], acc[mi][ni]);
    }
  }
}

// ---------------------------------------------------------------------------
// Kernel 1: QKV GEMM — 128x128 dbuf, 256 threads (2x2 waves, 64x64 wave
// tile, 32 MFMA/wave/iter), 64 KB LDS, 2/CU.  Each wave's 64x64 sub-tile
// covers one head on the V side.  Q pre-scaled by QSCALE.  V: LDS-bounce
// transpose with per-64-tile key permutation sigma(t)=(t&15)*4+((t>>4)&3).
// ---------------------------------------------------------------------------
__global__ __launch_bounds__(256) void qkv_gemm_kernel(
    const bf16_t* __restrict__ x, const bf16_t* __restrict__ w,
    const float* __restrict__ bias,
    bf16_t* __restrict__ qws, bf16_t* __restrict__ kws, bf16_t* __restrict__ vws)
{
  __shared__ __align__(16) bf16_t ldsA[2][128 * 64];   // 32 KB
  __shared__ __align__(16) bf16_t ldsB[2][128 * 64];   // 32 KB
  const int lane = threadIdx.x & 63;
  const int wv   = threadIdx.x >> 6;
  const int col  = lane & 15;
  const int quad = lane >> 4;
  const int wm = wv >> 1, wn = wv & 1;
  const int m0 = blockIdx.y * 128;
  const int n0 = blockIdx.x * 128;

  f32x4 acc[4][4] = {};
  gemm_mainloop_db<128, 128, 4, 4>(x, w, C, m0, n0,
                                   ldsA[0], ldsA[1], ldsB[0], ldsB[1], acc);

  const int which = n0 >> 10;          // block-uniform: 0=Q, 1=K, 2=V

  if (which == 2) {
    // ---- V path: LDS-bounce transpose (wave tile 64 t x 64 d = one head) --
    __syncthreads();                   // mainloop readers done; reuse ldsA
    bf16_t* vt = &ldsA[0][0] + wv * 4096;   // 8 KB wave-private region

#pragma unroll
    for (int ni = 0; ni < 4; ++ni) {
      const int n = n0 + wn * 64 + ni * 16 + col;
      const float bval = bias[n];
      const int dl = ni * 16 + col;    // 0..63 within wave region
#pragma unroll
      for (int r = 0; r < 4; ++r) {
        bf16x4 pw;
#pragma unroll
        for (int mi = 0; mi < 4; ++mi)
          pw[mi] = (bf16_t)(acc[mi][ni][r] + bval);
        // sigma base = (quad*4+r)*4; chunk k = (quad*4+r)>>1
        const int k = 2 * quad + (r >> 1);
        const int S = dl * 8 + (k ^ (dl & 7));
        *(bf16x4*)(vt + S * 8 + (r & 1) * 4) = pw;
      }
    }

    const int b   = (m0 + wm * 64) >> 11;
    const int t0w = (m0 + wm * 64) & (T - 1);    // 64-aligned
    const int h   = ((n0 + wn * 64) & (C - 1)) >> 6;   // one head per wave
    const size_t bh = (size_t)(b * H + h);
    const int lr8 = lane >> 3;
    const int c8  = lane & 7;
#pragma unroll
    for (int j = 0; j < 8; ++j) {
      const int dl = j * 8 + lr8;                // 0..63
      const int d  = dl;
      bf16x8 row = *(const bf16x8*)(vt + (dl * 8 + (c8 ^ (dl & 7))) * 8);
      *(bf16x8*)(vws + (bh * D + d) * T + t0w + c8 * 8) = row;
    }
  } else {
    // ---- Q/K path ----
#pragma unroll
    for (int ni = 0; ni < 4; ++ni) {
      const int n = n0 + wn * 64 + ni * 16 + col;
      const float bval = bias[n];
      const int c = n & (C - 1);
      const int h = c >> 6;
      const int d = c & 63;
#pragma unroll
      for (int mi = 0; mi < 4; ++mi) {
#pragma unroll
        for (int r = 0; r < 4; ++r) {
          const int m = m0 + wm * 64 + mi * 16 + quad * 4 + r;
          const int b = m >> 11;
          const int t = m & (T - 1);
          const size_t bh = (size_t)(b * H + h);
          if (which == 0)
            qws[(bh * T + t) * D + d] = (bf16_t)((acc[mi][ni][r] + bval) * QSCALE);
          else
            kws[(bh * T + t) * D + d] = (bf16_t)(acc[mi][ni][r] + bval);
        }
      }
    }
  }
}

// ---------------------------------------------------------------------------
// Kernel 2: causal flash attention — round-19 structure (measured best):
// paired hi/lo q-tiles per block (512 blocks, 33 tile-computes each), K and
// V fragments loaded ONCE per iteration and shared between both tiles'
// MFMAs.  48 KB LDS (K/V dbuf + separate Ph/Pl buffers).
// Round-24 finding: throughput is invariant to occupancy (9/15/18%) and
// work-splitting — phase-serial chain bound; this config is the floor of
// this decomposition.
// ---------------------------------------------------------------------------
__global__ __launch_bounds__(256) void attn_kernel(
    const bf16_t* __restrict__ qws, const bf16_t* __restrict__ kws,
    const bf16_t* __restrict__ vws, bf16_t* __restrict__ yws)
{
  const int id = blockIdx.x;
  const int bh = id & 31;
  const int pr = id >> 5;            // 0..15
  const int tid  = threadIdx.x;
  const int wv   = tid >> 6;
  const int lane = tid & 63;
  const int col  = lane & 15;
  const int quad = lane >> 4;

  const bf16_t* Q  = qws + (size_t)bh * T * D;
  const bf16_t* K  = kws + (size_t)bh * T * D;
  const bf16_t* Vt = vws + (size_t)bh * D * T;

  __shared__ __align__(16) bf16_t ldsK[2][64 * 64];      // 16 KB
  __shared__ __align__(16) bf16_t ldsV[2][64 * 64];      // 16 KB
  __shared__ __align__(16) bf16_t ldsPh_s[4][16 * 64];   // 8 KB
  __shared__ __align__(16) bf16_t ldsPl_s[4][16 * 64];   // 8 KB
  bf16_t* ldsPh = ldsPh_s[wv];
  bf16_t* ldsPl = ldsPl_s[wv];

  const int xs   = col & 7;
  const int cxq  = (quad ^ xs) * 8;
  const int lr8  = lane >> 3;
  const int ksrc = (lane & 7) ^ lr8;
  const int pxor = (quad & 1) * 4;
  const int b = bh >> 4;
  const int h = bh & 15;

  const int qt_h = 31 - pr, qt_l = pr;       // qt_l < qt_h always
  const int t0h = qt_h * 64, t0l = qt_l * 64;
  const int twh = t0h + 16 * wv, twl = t0l + 16 * wv;

  bf16x8 qfh0 = *(const bf16x8*)(Q + (size_t)(twh + col) * D + quad * 8);
  bf16x8 qfh1 = *(const bf16x8*)(Q + (size_t)(twh + col) * D + 32 + quad * 8);
  bf16x8 qfl0 = *(const bf16x8*)(Q + (size_t)(twl + col) * D + quad * 8);
  bf16x8 qfl1 = *(const bf16x8*)(Q + (size_t)(twl + col) * D + 32 + quad * 8);

  f32x4 oh[4] = {}, ol[4] = {};
  f32x4 lph = {}, lpl = {};

  // stage K/V tile `it` into LDS buffer (it & 1)
  auto stage = [&](int it) {
    const int sn = it * 64;
    bf16_t* dK = ldsK[it & 1];
    bf16_t* dV = ldsV[it & 1];
#pragma unroll
    for (int j = 0; j < 2; ++j) {
      GLOAD_LDS16(K + (size_t)(sn + 16 * wv + j * 8 + lr8) * D + ksrc * 8,
                  dK + (16 * wv + j * 8) * 64);
      GLOAD_LDS16(Vt + (size_t)(16 * wv + j * 8 + lr8) * T + sn + ksrc * 8,
                  dV + (16 * wv + j * 8) * 64);
    }
  };

  // One K/V tile against hi (always) and lo (compile-time LO) q-tiles.
  // K and V fragments loaded once, fed to both tiles' MFMAs.
  auto body = [&](auto LOC, const bf16_t* bK, const bf16_t* bV,
                  int s0, bool hdiag, bool ldiag) {
    constexpr bool LO = decltype(LOC)::value;
    f32x4 sch[4], scl[4];
    __builtin_amdgcn_s_setprio(1);
#pragma unroll
    for (int kb = 0; kb < 4; ++kb) {
      const bf16_t* kr = bK + (kb * 16 + col) * 64;
      bf16x8 kf0 = *(const bf16x8*)(kr + cxq);
      bf16x8 kf1 = *(const bf16x8*)(kr + (cxq ^ 32));
      f32x4 a = {};
      a = MFMA16(qfh0, kf0, a);
      a = MFMA16(qfh1, kf1, a);
      sch[kb] = a;
      if constexpr (LO) {
        f32x4 c = {};
        c = MFMA16(qfl0, kf0, c);
        c = MFMA16(qfl1, kf1, c);
        scl[kb] = c;
      }
    }
    __builtin_amdgcn_s_setprio(0);
#pragma unroll
    for (int r = 0; r < 4; ++r) {
      const int prow = (quad * 4 + r) * 64;
      const int pxr  = pxor + r;
      const int poff = prow + (((col >> 1) ^ pxr) * 8) + (col & 1) * 4;
      bf16x4 pw;
#pragma unroll
      for (int kb = 0; kb < 4; ++kb) {
        float p = __builtin_amdgcn_exp2f(sch[kb][r]);
        if (hdiag && (s0 + kb * 16 + col > twh + quad * 4 + r)) p = 0.0f;
        lph[r] += p;
        pw[kb] = (bf16_t)p;
      }
      *(bf16x4*)(ldsPh + poff) = pw;
      if constexpr (LO) {
        bf16x4 pl;
#pragma unroll
        for (int kb = 0; kb < 4; ++kb) {
          float p = __builtin_amdgcn_exp2f(scl[kb][r]);
          if (ldiag && (s0 + kb * 16 + col > twl + quad * 4 + r)) p = 0.0f;
          lpl[r] += p;
          pl[kb] = (bf16_t)p;
        }
        *(bf16x4*)(ldsPl + poff) = pl;
      }
    }
    __builtin_amdgcn_s_setprio(1);
#pragma unroll
    for (int ks = 0; ks < 2; ++ks) {
      const int xk = cxq ^ (ks * 32);
      bf16x8 pah = *(const bf16x8*)(ldsPh + col * 64 + xk);
      bf16x8 pal{};
      if constexpr (LO) pal = *(const bf16x8*)(ldsPl + col * 64 + xk);
#pragma unroll
      for (int ni = 0; ni < 4; ++ni) {
        bf16x8 vf = *(const bf16x8*)(bV + (ni * 16 + col) * 64 + xk);
        oh[ni] = MFMA16(pah, vf, oh[ni]);
        if constexpr (LO) ol[ni] = MFMA16(pal, vf, ol[ni]);
      }
    }
    __builtin_amdgcn_s_setprio(0);
  };

  // prologue: stage tile 0 into buffer 0
  stage(0);

  // Range A: both tiles interior
  for (int it = 0; it < qt_l; ++it) {
    __syncthreads();
    stage(it + 1);                       // it+1 <= qt_l < qt_h
    body(LoOn{}, ldsK[it & 1], ldsV[it & 1], it * 64, false, false);
  }
  // Peel it = qt_l: hi interior, lo diagonal
  {
    const int it = qt_l;
    __syncthreads();
    stage(it + 1);                       // qt_l+1 <= qt_h
    body(LoOn{}, ldsK[it & 1], ldsV[it & 1], it * 64, false, true);
  }
  // Range B: hi only, interior
  for (int it = qt_l + 1; it < qt_h; ++it) {
    __syncthreads();
    stage(it + 1);                       // it+1 <= qt_h
    body(LoOff{}, ldsK[it & 1], ldsV[it & 1], it * 64, false, false);
  }
  // Peel it = qt_h: hi diagonal, nothing left to stage
  {
    __syncthreads();
    body(LoOff{}, ldsK[qt_h & 1], ldsV[qt_h & 1], qt_h * 64, true, false);
  }

  // epilogue: reduce l, normalize, write Y for both tiles
#pragma unroll
  for (int r = 0; r < 4; ++r) {
    float l0 = lph[r], l1 = lpl[r];
#pragma unroll
    for (int off = 1; off < 16; off <<= 1) {
      l0 += __shfl_xor(l0, off);
      l1 += __shfl_xor(l1, off);
    }
    const float rl0 = 1.0f / l0, rl1 = 1.0f / l1;
    const int th = twh + quad * 4 + r;
    const int tl = twl + quad * 4 + r;
#pragma unroll
    for (int ni = 0; ni < 4; ++ni) {
      const int d = ni * 16 + col;
      yws[((size_t)(b * T + th)) * C + h * D + d] = (bf16_t)(oh[ni][r] * rl0);
      yws[((size_t)(b * T + tl)) * C + h * D + d] = (bf16_t)(ol[ni][r] * rl1);
    }
  }
}

// ---------------------------------------------------------------------------
// Kernel 3: output projection — 128x64 dbuf (48 KB LDS, 512 blocks = 3/CU,
// 16 MFMA/wave/iter), f32 output.
// ---------------------------------------------------------------------------
__global__ __launch_bounds__(256) void proj_gemm_kernel(
    const bf16_t* __restrict__ y, const bf16_t* __restrict__ w,
    const float* __restrict__ bias, float* __restrict__ out)
{
  __shared__ __align__(16) bf16_t ldsA[2][128 * 64];
  __shared__ __align__(16) bf16_t ldsB[2][64 * 64];
  const int lane = threadIdx.x & 63;
  const int wv   = threadIdx.x >> 6;
  const int col  = lane & 15;
  const int quad = lane >> 4;
  const int wm = wv >> 1, wn = wv & 1;
  const int m0 = blockIdx.y * 128;
  const int n0 = blockIdx.x * 64;

  f32x4 acc[4][2] = {};
  gemm_mainloop_db<128, 64, 4, 2>(y, w, C, m0, n0,
                                  ldsA[0], ldsA[1], ldsB[0], ldsB[1], acc);

#pragma unroll
  for (int ni = 0; ni < 2; ++ni) {
    const int n = n0 + wn * 32 + ni * 16 + col;
    const float bval = bias[n];
#pragma unroll
    for (int mi = 0; mi < 4; ++mi) {
#pragma unroll
      for (int r = 0; r < 4; ++r) {
        const int m = m0 + wm * 64 + mi * 16 + quad * 4 + r;
        out[(size_t)m * C + n] = acc[mi][ni][r] + bval;
      }
    }
  }
}

// ---------------------------------------------------------------------------
extern "C" void kernel_launch(void* const* d_in, const int* in_sizes, int n_in,
                              void* d_out, int out_size, void* d_ws, size_t ws_size,
                              hipStream_t stream) {
  const float* x      = (const float*)d_in[0];
  const float* attn_w = (const float*)d_in[1];
  const float* attn_b = (const float*)d_in[2];
  const float* proj_w = (const float*)d_in[3];
  const float* proj_b = (const float*)d_in[4];
  float* out = (float*)d_out;

  const size_t E = (size_t)B * H * T * D;   // 4,194,304
  char* ws = (char*)d_ws;
  bf16_t* qws = (bf16_t*)(ws);
  bf16_t* kws = (bf16_t*)(ws + 2 * E);
  bf16_t* vws = (bf16_t*)(ws + 4 * E);
  bf16_t* yws = (bf16_t*)(ws + 6 * E);
  bf16_t* xb  = (bf16_t*)(ws + 8 * E);
  bf16_t* awb = (bf16_t*)(ws + 10 * E);
  bf16_t* pwb = (bf16_t*)(ws + 11 * E + E / 2);

  cvt_kernel<<<4096, 256, 0, stream>>>(x, xb, attn_w, awb, proj_w, pwb);
  qkv_gemm_kernel<<<dim3(NQKV / 128, M / 128), 256, 0, stream>>>(
      xb, awb, attn_b, qws, kws, vws);
  attn_kernel<<<512, 256, 0, stream>>>(qws, kws, vws, yws);
  proj_gemm_kernel<<<dim3(C / 64, M / 128), 256, 0, stream>>>(
      yws, pwb, proj_b, out);
}

// Round 11
// 168.022 us; speedup vs baseline: 1.0099x; 1.0068x over previous
//
#include <hip/hip_runtime.h>
#include <hip/hip_bf16.h>

typedef __bf16 bf16_t;
typedef __bf16 bf16x2 __attribute__((ext_vector_type(2)));
typedef __bf16 bf16x4 __attribute__((ext_vector_type(4)));
typedef __bf16 bf16x8 __attribute__((ext_vector_type(8)));
typedef float f32x4 __attribute__((ext_vector_type(4)));
typedef float f32x8 __attribute__((ext_vector_type(8)));
typedef unsigned u32x4 __attribute__((ext_vector_type(4)));

#define MFMA16(a, b, c) __builtin_amdgcn_mfma_f32_16x16x32_bf16(a, b, c, 0, 0, 0)

#define GLOAD_LDS16(g, l)                                              \
  __builtin_amdgcn_global_load_lds(                                    \
      (const __attribute__((address_space(1))) unsigned int*)(g),      \
      (__attribute__((address_space(3))) unsigned int*)(l), 16, 0, 0)

constexpr int B = 2, T = 2048, C = 1024, H = 16, D = 64;
constexpr int NQKV = 3 * C;   // 3072
constexpr int M = B * T;      // 4096

// Q pre-scaled at QKV time by 1/sqrt(D)*log2(e): attn softmax = bare exp2.
#define QSCALE 0.18033688011112042f

struct LoOn  { static constexpr bool value = true;  };
struct LoOff { static constexpr bool value = false; };

// ---------------------------------------------------------------------------
// Kernel 0: f32 -> bf16 convert (x, attn_w, proj_w).  Exact 1D grid.
// ---------------------------------------------------------------------------
__global__ __launch_bounds__(256) void cvt_kernel(
    const float* __restrict__ s0, bf16_t* __restrict__ d0,
    const float* __restrict__ s1, bf16_t* __restrict__ d1,
    const float* __restrict__ s2, bf16_t* __restrict__ d2)
{
  const int blk = blockIdx.x;
  const float* s; bf16_t* d; int base;
  if (blk < 2048)      { s = s0; d = d0; base = blk; }
  else if (blk < 3584) { s = s1; d = d1; base = blk - 2048; }
  else                 { s = s2; d = d2; base = blk - 3584; }
  const int idx = (base * 256 + threadIdx.x) * 8;
  f32x8 t = *(const f32x8*)(s + idx);
  bf16x8 r;
#pragma unroll
  for (int j = 0; j < 8; ++j) r[j] = (bf16_t)t[j];
  *(bf16x8*)(d + idx) = r;
}

// ---------------------------------------------------------------------------
// GEMM mainloop (dbuf): BM x BN block tile, double-buffered LDS, one barrier
// per BK=64 iteration, XOR chunk swizzle, width-16 global_load_lds.
// 4 waves as 2x2; wave tile (MI*16) x (NI*16).
// ---------------------------------------------------------------------------
template<int BM, int BN, int MI, int NI>
__device__ __forceinline__ void gemm_mainloop_db(
    const bf16_t* __restrict__ A, const bf16_t* __restrict__ Wt,
    const int K, const int m0, const int n0,
    bf16_t* ldsA0, bf16_t* ldsA1, bf16_t* ldsB0, bf16_t* ldsB1,
    f32x4 acc[MI][NI])
{
  const int tid  = threadIdx.x;
  const int wv   = tid >> 6;
  const int lane = tid & 63;
  const int col  = lane & 15;
  const int quad = lane >> 4;
  const int lr8  = lane >> 3;
  const int cpos = lane & 7;
  const int wm = wv >> 1, wn = wv & 1;
  constexpr int AJ = BM / 32;
  constexpr int ARW = BM / 4;
  constexpr int BJ = BN / 32;
  constexpr int BRW = BN / 4;

  const bf16_t* ag[AJ]; const bf16_t* bg[BJ];
#pragma unroll
  for (int j = 0; j < AJ; ++j)
    ag[j] = A + (size_t)(m0 + wv * ARW + j * 8 + lr8) * K + (cpos ^ lr8) * 8;
#pragma unroll
  for (int j = 0; j < BJ; ++j)
    bg[j] = Wt + (size_t)(n0 + wv * BRW + j * 8 + lr8) * K + (cpos ^ lr8) * 8;

  const int xa = quad ^ (col & 7);
  const int niter = K / 64;

#pragma unroll
  for (int j = 0; j < AJ; ++j)
    GLOAD_LDS16(ag[j], ldsA0 + (wv * ARW + j * 8) * 64);
#pragma unroll
  for (int j = 0; j < BJ; ++j)
    GLOAD_LDS16(bg[j], ldsB0 + (wv * BRW + j * 8) * 64);

  for (int it = 0; it < niter; ++it) {
    __syncthreads();
    const bf16_t* cA = (it & 1) ? ldsA1 : ldsA0;
    const bf16_t* cB = (it & 1) ? ldsB1 : ldsB0;
    if (it + 1 < niter) {
      bf16_t* nA = (it & 1) ? ldsA0 : ldsA1;
      bf16_t* nB = (it & 1) ? ldsB0 : ldsB1;
      const int off = (it + 1) * 64;
#pragma unroll
      for (int j = 0; j < AJ; ++j)
        GLOAD_LDS16(ag[j] + off, nA + (wv * ARW + j * 8) * 64);
#pragma unroll
      for (int j = 0; j < BJ; ++j)
        GLOAD_LDS16(bg[j] + off, nB + (wv * BRW + j * 8) * 64);
    }
#pragma unroll
    for (int ks = 0; ks < 2; ++ks) {
      const int xk = (xa ^ (ks * 4)) * 8;
      bf16x8 af[MI], bfr[NI];
#pragma unroll
      for (int mi = 0; mi < MI; ++mi)
        af[mi] = *(const bf16x8*)(cA + (wm * (MI * 16) + mi * 16 + col) * 64 + xk);
#pragma unroll
      for (int ni = 0; ni < NI; ++ni)
        bfr[ni] = *(const bf16x8*)(cB + (wn * (NI * 16) + ni * 16 + col) * 64 + xk);
#pragma unroll
      for (int mi = 0; mi < MI; ++mi)
#pragma unroll
        for (int ni = 0; ni < NI; ++ni)
          acc[mi][ni] = MFMA16(af[mi], bfr[ni], acc[mi][ni]);
    }
  }
}

// ---------------------------------------------------------------------------
// Kernel 1: QKV GEMM — 128x128 dbuf, 256 threads (2x2 waves, 64x64 wave
// tile, 32 MFMA/wave/iter), 64 KB LDS, 2/CU.  Q pre-scaled by QSCALE.
// V: LDS-bounce transpose, sigma(t) = per-64 key permutation.
// ---------------------------------------------------------------------------
__global__ __launch_bounds__(256) void qkv_gemm_kernel(
    const bf16_t* __restrict__ x, const bf16_t* __restrict__ w,
    const float* __restrict__ bias,
    bf16_t* __restrict__ qws, bf16_t* __restrict__ kws, bf16_t* __restrict__ vws)
{
  __shared__ __align__(16) bf16_t ldsA[2][128 * 64];   // 32 KB
  __shared__ __align__(16) bf16_t ldsB[2][128 * 64];   // 32 KB
  const int lane = threadIdx.x & 63;
  const int wv   = threadIdx.x >> 6;
  const int col  = lane & 15;
  const int quad = lane >> 4;
  const int wm = wv >> 1, wn = wv & 1;
  const int m0 = blockIdx.y * 128;
  const int n0 = blockIdx.x * 128;

  f32x4 acc[4][4] = {};
  gemm_mainloop_db<128, 128, 4, 4>(x, w, C, m0, n0,
                                   ldsA[0], ldsA[1], ldsB[0], ldsB[1], acc);

  const int which = n0 >> 10;          // block-uniform: 0=Q, 1=K, 2=V

  if (which == 2) {
    // ---- V path: LDS-bounce transpose (wave tile 64 t x 64 d = one head) --
    __syncthreads();                   // mainloop readers done; reuse ldsA
    bf16_t* vt = &ldsA[0][0] + wv * 4096;   // 8 KB wave-private region

#pragma unroll
    for (int ni = 0; ni < 4; ++ni) {
      const int n = n0 + wn * 64 + ni * 16 + col;
      const float bval = bias[n];
      const int dl = ni * 16 + col;    // 0..63 within wave region
#pragma unroll
      for (int r = 0; r < 4; ++r) {
        bf16x4 pw;
#pragma unroll
        for (int mi = 0; mi < 4; ++mi)
          pw[mi] = (bf16_t)(acc[mi][ni][r] + bval);
        // sigma base = (quad*4+r)*4; chunk k = (quad*4+r)>>1
        const int k = 2 * quad + (r >> 1);
        const int S = dl * 8 + (k ^ (dl & 7));
        *(bf16x4*)(vt + S * 8 + (r & 1) * 4) = pw;
      }
    }

    const int b   = (m0 + wm * 64) >> 11;
    const int t0w = (m0 + wm * 64) & (T - 1);    // 64-aligned
    const int h   = ((n0 + wn * 64) & (C - 1)) >> 6;   // one head per wave
    const size_t bh = (size_t)(b * H + h);
    const int lr8 = lane >> 3;
    const int c8  = lane & 7;
#pragma unroll
    for (int j = 0; j < 8; ++j) {
      const int dl = j * 8 + lr8;                // 0..63
      const int d  = dl;
      bf16x8 row = *(const bf16x8*)(vt + (dl * 8 + (c8 ^ (dl & 7))) * 8);
      *(bf16x8*)(vws + (bh * D + d) * T + t0w + c8 * 8) = row;
    }
  } else {
    // ---- Q/K path ----
#pragma unroll
    for (int ni = 0; ni < 4; ++ni) {
      const int n = n0 + wn * 64 + ni * 16 + col;
      const float bval = bias[n];
      const int c = n & (C - 1);
      const int h = c >> 6;
      const int d = c & 63;
#pragma unroll
      for (int mi = 0; mi < 4; ++mi) {
#pragma unroll
        for (int r = 0; r < 4; ++r) {
          const int m = m0 + wm * 64 + mi * 16 + quad * 4 + r;
          const int b = m >> 11;
          const int t = m & (T - 1);
          const size_t bh = (size_t)(b * H + h);
          if (which == 0)
            qws[(bh * T + t) * D + d] = (bf16_t)((acc[mi][ni][r] + bval) * QSCALE);
          else
            kws[(bh * T + t) * D + d] = (bf16_t)(acc[mi][ni][r] + bval);
        }
      }
    }
  }
}

// ---------------------------------------------------------------------------
// Kernel 2: causal flash attention — round 25: swapped-operand QK^T +
// IN-REGISTER softmax/P redistribution (no P LDS bounce).
//   S^T = MFMA(kf, qf): lane holds q = col, t = kb*16 + quad*4 + r.
//   K/Q/V loads identical to previous kernel (operand layouts coincide).
//   PV A-frag built in registers: pack P across kb at fixed r, then
//   8 shfl + 4 select per ks (srcLane = col + 16*(2ks + quad>>1), register
//   pair by quad&1) — matches V's sigma-permuted t order (verified against
//   the old P-write swizzle: logical pos g*8+4h+kb holds t=kb*16+2g+h).
//   l is lane-local (q=col): 2 shfl_xor at end.  LDS 32 KB (K/V dbuf only).
// Paired hi/lo q-tiles per block (512 blocks); K/V fragments shared.
// ---------------------------------------------------------------------------
__global__ __launch_bounds__(256) void attn_kernel(
    const bf16_t* __restrict__ qws, const bf16_t* __restrict__ kws,
    const bf16_t* __restrict__ vws, bf16_t* __restrict__ yws)
{
  const int id = blockIdx.x;
  const int bh = id & 31;
  const int pr = id >> 5;            // 0..15
  const int tid  = threadIdx.x;
  const int wv   = tid >> 6;
  const int lane = tid & 63;
  const int col  = lane & 15;
  const int quad = lane >> 4;

  const bf16_t* Q  = qws + (size_t)bh * T * D;
  const bf16_t* K  = kws + (size_t)bh * T * D;
  const bf16_t* Vt = vws + (size_t)bh * D * T;

  __shared__ __align__(16) bf16_t ldsK[2][64 * 64];      // 16 KB
  __shared__ __align__(16) bf16_t ldsV[2][64 * 64];      // 16 KB

  const int xs   = col & 7;
  const int cxq  = (quad ^ xs) * 8;
  const int lr8  = lane >> 3;
  const int ksrc = (lane & 7) ^ lr8;
  const int b = bh >> 4;
  const int h = bh & 15;

  const int qt_h = 31 - pr, qt_l = pr;       // qt_l < qt_h always
  const int t0h = qt_h * 64, t0l = qt_l * 64;
  const int twh = t0h + 16 * wv, twl = t0l + 16 * wv;

  bf16x8 qfh0 = *(const bf16x8*)(Q + (size_t)(twh + col) * D + quad * 8);
  bf16x8 qfh1 = *(const bf16x8*)(Q + (size_t)(twh + col) * D + 32 + quad * 8);
  bf16x8 qfl0 = *(const bf16x8*)(Q + (size_t)(twl + col) * D + quad * 8);
  bf16x8 qfl1 = *(const bf16x8*)(Q + (size_t)(twl + col) * D + 32 + quad * 8);

  f32x4 oh[4] = {}, ol[4] = {};
  float lqh = 0.0f, lql = 0.0f;

  // stage K/V tile `it` into LDS buffer (it & 1)
  auto stage = [&](int it) {
    const int sn = it * 64;
    bf16_t* dK = ldsK[it & 1];
    bf16_t* dV = ldsV[it & 1];
#pragma unroll
    for (int j = 0; j < 2; ++j) {
      GLOAD_LDS16(K + (size_t)(sn + 16 * wv + j * 8 + lr8) * D + ksrc * 8,
                  dK + (16 * wv + j * 8) * 64);
      GLOAD_LDS16(Vt + (size_t)(16 * wv + j * 8 + lr8) * T + sn + ksrc * 8,
                  dV + (16 * wv + j * 8) * 64);
    }
  };

  // One K/V tile against hi (always) and lo (compile-time LO) q-tiles.
  // K and V fragments loaded once, fed to both tiles' MFMAs.
  auto body = [&](auto LOC, const bf16_t* bK, const bf16_t* bV,
                  int s0, bool hdiag, bool ldiag) {
    constexpr bool LO = decltype(LOC)::value;
    f32x4 sch[4], scl[4];
    __builtin_amdgcn_s_setprio(1);
#pragma unroll
    for (int kb = 0; kb < 4; ++kb) {
      const bf16_t* kr = bK + (kb * 16 + col) * 64;
      bf16x8 kf0 = *(const bf16x8*)(kr + cxq);
      bf16x8 kf1 = *(const bf16x8*)(kr + (cxq ^ 32));
      f32x4 a = {};
      a = MFMA16(kf0, qfh0, a);          // swapped: S^T, q = col
      a = MFMA16(kf1, qfh1, a);
      sch[kb] = a;
      if constexpr (LO) {
        f32x4 c = {};
        c = MFMA16(kf0, qfl0, c);
        c = MFMA16(kf1, qfl1, c);
        scl[kb] = c;
      }
    }
    __builtin_amdgcn_s_setprio(0);
    // exp2 + mask + l-accum; pack across kb at fixed r: qk[r][i] =
    // (bf16(p[2i][r]) | bf16(p[2i+1][r])<<16)
    unsigned qh[4][2], qlp[4][2];
#pragma unroll
    for (int r = 0; r < 4; ++r) {
#pragma unroll
      for (int i = 0; i < 2; ++i) {
        float p0 = __builtin_amdgcn_exp2f(sch[2 * i][r]);
        float p1 = __builtin_amdgcn_exp2f(sch[2 * i + 1][r]);
        if (hdiag) {
          if (s0 + (2 * i) * 16     + quad * 4 + r > twh + col) p0 = 0.0f;
          if (s0 + (2 * i + 1) * 16 + quad * 4 + r > twh + col) p1 = 0.0f;
        }
        lqh += p0 + p1;
        bf16x2 t2; t2[0] = (bf16_t)p0; t2[1] = (bf16_t)p1;
        qh[r][i] = __builtin_bit_cast(unsigned, t2);
        if constexpr (LO) {
          float q0 = __builtin_amdgcn_exp2f(scl[2 * i][r]);
          float q1 = __builtin_amdgcn_exp2f(scl[2 * i + 1][r]);
          if (ldiag) {
            if (s0 + (2 * i) * 16     + quad * 4 + r > twl + col) q0 = 0.0f;
            if (s0 + (2 * i + 1) * 16 + quad * 4 + r > twl + col) q1 = 0.0f;
          }
          lql += q0 + q1;
          bf16x2 s2; s2[0] = (bf16_t)q0; s2[1] = (bf16_t)q1;
          qlp[r][i] = __builtin_bit_cast(unsigned, s2);
        }
      }
    }
    // redistribute to PV A-fragments + PV MFMAs
    const int slbase = col + ((quad >> 1) << 4);
    const bool qodd = (quad & 1) != 0;
#pragma unroll
    for (int ks = 0; ks < 2; ++ks) {
      const int sl = slbase + ks * 32;
      u32x4 uh;
      {
        int a0 = __shfl((int)qh[0][0], sl), a1 = __shfl((int)qh[0][1], sl);
        int a2 = __shfl((int)qh[1][0], sl), a3 = __shfl((int)qh[1][1], sl);
        int b0 = __shfl((int)qh[2][0], sl), b1 = __shfl((int)qh[2][1], sl);
        int b2 = __shfl((int)qh[3][0], sl), b3 = __shfl((int)qh[3][1], sl);
        uh[0] = (unsigned)(qodd ? b0 : a0); uh[1] = (unsigned)(qodd ? b1 : a1);
        uh[2] = (unsigned)(qodd ? b2 : a2); uh[3] = (unsigned)(qodd ? b3 : a3);
      }
      bf16x8 pah = __builtin_bit_cast(bf16x8, uh);
      bf16x8 pal{};
      if constexpr (LO) {
        u32x4 ul;
        int a0 = __shfl((int)qlp[0][0], sl), a1 = __shfl((int)qlp[0][1], sl);
        int a2 = __shfl((int)qlp[1][0], sl), a3 = __shfl((int)qlp[1][1], sl);
        int b0 = __shfl((int)qlp[2][0], sl), b1 = __shfl((int)qlp[2][1], sl);
        int b2 = __shfl((int)qlp[3][0], sl), b3 = __shfl((int)qlp[3][1], sl);
        ul[0] = (unsigned)(qodd ? b0 : a0); ul[1] = (unsigned)(qodd ? b1 : a1);
        ul[2] = (unsigned)(qodd ? b2 : a2); ul[3] = (unsigned)(qodd ? b3 : a3);
        pal = __builtin_bit_cast(bf16x8, ul);
      }
      const int xk = cxq ^ (ks * 32);
      __builtin_amdgcn_s_setprio(1);
#pragma unroll
      for (int ni = 0; ni < 4; ++ni) {
        bf16x8 vf = *(const bf16x8*)(bV + (ni * 16 + col) * 64 + xk);
        oh[ni] = MFMA16(pah, vf, oh[ni]);
        if constexpr (LO) ol[ni] = MFMA16(pal, vf, ol[ni]);
      }
      __builtin_amdgcn_s_setprio(0);
    }
  };

  // prologue: stage tile 0 into buffer 0
  stage(0);

  // Range A: both tiles interior
  for (int it = 0; it < qt_l; ++it) {
    __syncthreads();
    stage(it + 1);                       // it+1 <= qt_l < qt_h
    body(LoOn{}, ldsK[it & 1], ldsV[it & 1], it * 64, false, false);
  }
  // Peel it = qt_l: hi interior, lo diagonal
  {
    const int it = qt_l;
    __syncthreads();
    stage(it + 1);                       // qt_l+1 <= qt_h
    body(LoOn{}, ldsK[it & 1], ldsV[it & 1], it * 64, false, true);
  }
  // Range B: hi only, interior
  for (int it = qt_l + 1; it < qt_h; ++it) {
    __syncthreads();
    stage(it + 1);                       // it+1 <= qt_h
    body(LoOff{}, ldsK[it & 1], ldsV[it & 1], it * 64, false, false);
  }
  // Peel it = qt_h: hi diagonal, nothing left to stage
  {
    __syncthreads();
    body(LoOff{}, ldsK[qt_h & 1], ldsV[qt_h & 1], qt_h * 64, true, false);
  }

  // epilogue: reduce l over quads (q = col is lane-local), normalize, write
  lqh += __shfl_xor(lqh, 16); lqh += __shfl_xor(lqh, 32);
  lql += __shfl_xor(lql, 16); lql += __shfl_xor(lql, 32);
#pragma unroll
  for (int r = 0; r < 4; ++r) {
    const float rl0 = 1.0f / __shfl(lqh, quad * 4 + r);
    const float rl1 = 1.0f / __shfl(lql, quad * 4 + r);
    const int th = twh + quad * 4 + r;
    const int tl = twl + quad * 4 + r;
#pragma unroll
    for (int ni = 0; ni < 4; ++ni) {
      const int d = ni * 16 + col;
      yws[((size_t)(b * T + th)) * C + h * D + d] = (bf16_t)(oh[ni][r] * rl0);
      yws[((size_t)(b * T + tl)) * C + h * D + d] = (bf16_t)(ol[ni][r] * rl1);
    }
  }
}

// ---------------------------------------------------------------------------
// Kernel 3: output projection — 128x64 dbuf (48 KB LDS, 512 blocks = 3/CU,
// 16 MFMA/wave/iter), f32 output.
// ---------------------------------------------------------------------------
__global__ __launch_bounds__(256) void proj_gemm_kernel(
    const bf16_t* __restrict__ y, const bf16_t* __restrict__ w,
    const float* __restrict__ bias, float* __restrict__ out)
{
  __shared__ __align__(16) bf16_t ldsA[2][128 * 64];
  __shared__ __align__(16) bf16_t ldsB[2][64 * 64];
  const int lane = threadIdx.x & 63;
  const int wv   = threadIdx.x >> 6;
  const int col  = lane & 15;
  const int quad = lane >> 4;
  const int wm = wv >> 1, wn = wv & 1;
  const int m0 = blockIdx.y * 128;
  const int n0 = blockIdx.x * 64;

  f32x4 acc[4][2] = {};
  gemm_mainloop_db<128, 64, 4, 2>(y, w, C, m0, n0,
                                  ldsA[0], ldsA[1], ldsB[0], ldsB[1], acc);

#pragma unroll
  for (int ni = 0; ni < 2; ++ni) {
    const int n = n0 + wn * 32 + ni * 16 + col;
    const float bval = bias[n];
#pragma unroll
    for (int mi = 0; mi < 4; ++mi) {
#pragma unroll
      for (int r = 0; r < 4; ++r) {
        const int m = m0 + wm * 64 + mi * 16 + quad * 4 + r;
        out[(size_t)m * C + n] = acc[mi][ni][r] + bval;
      }
    }
  }
}

// ---------------------------------------------------------------------------
extern "C" void kernel_launch(void* const* d_in, const int* in_sizes, int n_in,
                              void* d_out, int out_size, void* d_ws, size_t ws_size,
                              hipStream_t stream) {
  const float* x      = (const float*)d_in[0];
  const float* attn_w = (const float*)d_in[1];
  const float* attn_b = (const float*)d_in[2];
  const float* proj_w = (const float*)d_in[3];
  const float* proj_b = (const float*)d_in[4];
  float* out = (float*)d_out;

  const size_t E = (size_t)B * H * T * D;   // 4,194,304
  char* ws = (char*)d_ws;
  bf16_t* qws = (bf16_t*)(ws);
  bf16_t* kws = (bf16_t*)(ws + 2 * E);
  bf16_t* vws = (bf16_t*)(ws + 4 * E);
  bf16_t* yws = (bf16_t*)(ws + 6 * E);
  bf16_t* xb  = (bf16_t*)(ws + 8 * E);
  bf16_t* awb = (bf16_t*)(ws + 10 * E);
  bf16_t* pwb = (bf16_t*)(ws + 11 * E + E / 2);

  cvt_kernel<<<4096, 256, 0, stream>>>(x, xb, attn_w, awb, proj_w, pwb);
  qkv_gemm_kernel<<<dim3(NQKV / 128, M / 128), 256, 0, stream>>>(
      xb, awb, attn_b, qws, kws, vws);
  attn_kernel<<<512, 256, 0, stream>>>(qws, kws, vws, yws);
  proj_gemm_kernel<<<dim3(C / 64, M / 128), 256, 0, stream>>>(
      yws, pwb, proj_b, out);
}

// Round 12
// 167.475 us; speedup vs baseline: 1.0132x; 1.0033x over previous
//
#include <hip/hip_runtime.h>
#include <hip/hip_bf16.h>

typedef __bf16 bf16_t;
typedef __bf16 bf16x4 __attribute__((ext_vector_type(4)));
typedef __bf16 bf16x8 __attribute__((ext_vector_type(8)));
typedef float f32x4 __attribute__((ext_vector_type(4)));
typedef float f32x8 __attribute__((ext_vector_type(8)));

#define MFMA16(a, b, c) __builtin_amdgcn_mfma_f32_16x16x32_bf16(a, b, c, 0, 0, 0)

#define GLOAD_LDS16(g, l)                                              \
  __builtin_amdgcn_global_load_lds(                                    \
      (const __attribute__((address_space(1))) unsigned int*)(g),      \
      (__attribute__((address_space(3))) unsigned int*)(l), 16, 0, 0)

constexpr int B = 2, T = 2048, C = 1024, H = 16, D = 64;
constexpr int NQKV = 3 * C;   // 3072
constexpr int M = B * T;      // 4096

// Q pre-scaled at QKV time by 1/sqrt(D)*log2(e): attn softmax = bare exp2.
#define QSCALE 0.18033688011112042f

struct LoOn  { static constexpr bool value = true;  };
struct LoOff { static constexpr bool value = false; };

// ---------------------------------------------------------------------------
// Kernel 0: f32 -> bf16 convert (x, attn_w, proj_w).  Exact 1D grid.
// ---------------------------------------------------------------------------
__global__ __launch_bounds__(256) void cvt_kernel(
    const float* __restrict__ s0, bf16_t* __restrict__ d0,
    const float* __restrict__ s1, bf16_t* __restrict__ d1,
    const float* __restrict__ s2, bf16_t* __restrict__ d2)
{
  const int blk = blockIdx.x;
  const float* s; bf16_t* d; int base;
  if (blk < 2048)      { s = s0; d = d0; base = blk; }
  else if (blk < 3584) { s = s1; d = d1; base = blk - 2048; }
  else                 { s = s2; d = d2; base = blk - 3584; }
  const int idx = (base * 256 + threadIdx.x) * 8;
  f32x8 t = *(const f32x8*)(s + idx);
  bf16x8 r;
#pragma unroll
  for (int j = 0; j < 8; ++j) r[j] = (bf16_t)t[j];
  *(bf16x8*)(d + idx) = r;
}

// ---------------------------------------------------------------------------
// GEMM mainloop (dbuf): BM x BN block tile, double-buffered LDS, one barrier
// per BK=64 iteration, XOR chunk swizzle, width-16 global_load_lds.
// 4 waves as 2x2; wave tile (MI*16) x (NI*16).
// ---------------------------------------------------------------------------
template<int BM, int BN, int MI, int NI>
__device__ __forceinline__ void gemm_mainloop_db(
    const bf16_t* __restrict__ A, const bf16_t* __restrict__ Wt,
    const int K, const int m0, const int n0,
    bf16_t* ldsA0, bf16_t* ldsA1, bf16_t* ldsB0, bf16_t* ldsB1,
    f32x4 acc[MI][NI])
{
  const int tid  = threadIdx.x;
  const int wv   = tid >> 6;
  const int lane = tid & 63;
  const int col  = lane & 15;
  const int quad = lane >> 4;
  const int lr8  = lane >> 3;
  const int cpos = lane & 7;
  const int wm = wv >> 1, wn = wv & 1;
  constexpr int AJ = BM / 32;
  constexpr int ARW = BM / 4;
  constexpr int BJ = BN / 32;
  constexpr int BRW = BN / 4;

  const bf16_t* ag[AJ]; const bf16_t* bg[BJ];
#pragma unroll
  for (int j = 0; j < AJ; ++j)
    ag[j] = A + (size_t)(m0 + wv * ARW + j * 8 + lr8) * K + (cpos ^ lr8) * 8;
#pragma unroll
  for (int j = 0; j < BJ; ++j)
    bg[j] = Wt + (size_t)(n0 + wv * BRW + j * 8 + lr8) * K + (cpos ^ lr8) * 8;

  const int xa = quad ^ (col & 7);
  const int niter = K / 64;

#pragma unroll
  for (int j = 0; j < AJ; ++j)
    GLOAD_LDS16(ag[j], ldsA0 + (wv * ARW + j * 8) * 64);
#pragma unroll
  for (int j = 0; j < BJ; ++j)
    GLOAD_LDS16(bg[j], ldsB0 + (wv * BRW + j * 8) * 64);

  for (int it = 0; it < niter; ++it) {
    __syncthreads();
    const bf16_t* cA = (it & 1) ? ldsA1 : ldsA0;
    const bf16_t* cB = (it & 1) ? ldsB1 : ldsB0;
    if (it + 1 < niter) {
      bf16_t* nA = (it & 1) ? ldsA0 : ldsA1;
      bf16_t* nB = (it & 1) ? ldsB0 : ldsB1;
      const int off = (it + 1) * 64;
#pragma unroll
      for (int j = 0; j < AJ; ++j)
        GLOAD_LDS16(ag[j] + off, nA + (wv * ARW + j * 8) * 64);
#pragma unroll
      for (int j = 0; j < BJ; ++j)
        GLOAD_LDS16(bg[j] + off, nB + (wv * BRW + j * 8) * 64);
    }
#pragma unroll
    for (int ks = 0; ks < 2; ++ks) {
      const int xk = (xa ^ (ks * 4)) * 8;
      bf16x8 af[MI], bfr[NI];
#pragma unroll
      for (int mi = 0; mi < MI; ++mi)
        af[mi] = *(const bf16x8*)(cA + (wm * (MI * 16) + mi * 16 + col) * 64 + xk);
#pragma unroll
      for (int ni = 0; ni < NI; ++ni)
        bfr[ni] = *(const bf16x8*)(cB + (wn * (NI * 16) + ni * 16 + col) * 64 + xk);
#pragma unroll
      for (int mi = 0; mi < MI; ++mi)
#pragma unroll
        for (int ni = 0; ni < NI; ++ni)
          acc[mi][ni] = MFMA16(af[mi], bfr[ni], acc[mi][ni]);
    }
  }
}

// ---------------------------------------------------------------------------
// Kernel 1: QKV GEMM — 128x128 dbuf, 256 threads (2x2 waves, 64x64 wave
// tile, 32 MFMA/wave/iter), 64 KB LDS, 2/CU.  Q pre-scaled by QSCALE.
// V: LDS-bounce transpose, sigma(t) = per-64 key permutation.
// ---------------------------------------------------------------------------
__global__ __launch_bounds__(256) void qkv_gemm_kernel(
    const bf16_t* __restrict__ x, const bf16_t* __restrict__ w,
    const float* __restrict__ bias,
    bf16_t* __restrict__ qws, bf16_t* __restrict__ kws, bf16_t* __restrict__ vws)
{
  __shared__ __align__(16) bf16_t ldsA[2][128 * 64];   // 32 KB
  __shared__ __align__(16) bf16_t ldsB[2][128 * 64];   // 32 KB
  const int lane = threadIdx.x & 63;
  const int wv   = threadIdx.x >> 6;
  const int col  = lane & 15;
  const int quad = lane >> 4;
  const int wm = wv >> 1, wn = wv & 1;
  const int m0 = blockIdx.y * 128;
  const int n0 = blockIdx.x * 128;

  f32x4 acc[4][4] = {};
  gemm_mainloop_db<128, 128, 4, 4>(x, w, C, m0, n0,
                                   ldsA[0], ldsA[1], ldsB[0], ldsB[1], acc);

  const int which = n0 >> 10;          // block-uniform: 0=Q, 1=K, 2=V

  if (which == 2) {
    // ---- V path: LDS-bounce transpose (wave tile 64 t x 64 d = one head) --
    __syncthreads();                   // mainloop readers done; reuse ldsA
    bf16_t* vt = &ldsA[0][0] + wv * 4096;   // 8 KB wave-private region

#pragma unroll
    for (int ni = 0; ni < 4; ++ni) {
      const int n = n0 + wn * 64 + ni * 16 + col;
      const float bval = bias[n];
      const int dl = ni * 16 + col;    // 0..63 within wave region
#pragma unroll
      for (int r = 0; r < 4; ++r) {
        bf16x4 pw;
#pragma unroll
        for (int mi = 0; mi < 4; ++mi)
          pw[mi] = (bf16_t)(acc[mi][ni][r] + bval);
        // sigma base = (quad*4+r)*4; chunk k = (quad*4+r)>>1
        const int k = 2 * quad + (r >> 1);
        const int S = dl * 8 + (k ^ (dl & 7));
        *(bf16x4*)(vt + S * 8 + (r & 1) * 4) = pw;
      }
    }

    const int b   = (m0 + wm * 64) >> 11;
    const int t0w = (m0 + wm * 64) & (T - 1);    // 64-aligned
    const int h   = ((n0 + wn * 64) & (C - 1)) >> 6;   // one head per wave
    const size_t bh = (size_t)(b * H + h);
    const int lr8 = lane >> 3;
    const int c8  = lane & 7;
#pragma unroll
    for (int j = 0; j < 8; ++j) {
      const int dl = j * 8 + lr8;                // 0..63
      const int d  = dl;
      bf16x8 row = *(const bf16x8*)(vt + (dl * 8 + (c8 ^ (dl & 7))) * 8);
      *(bf16x8*)(vws + (bh * D + d) * T + t0w + c8 * 8) = row;
    }
  } else {
    // ---- Q/K path ----
#pragma unroll
    for (int ni = 0; ni < 4; ++ni) {
      const int n = n0 + wn * 64 + ni * 16 + col;
      const float bval = bias[n];
      const int c = n & (C - 1);
      const int h = c >> 6;
      const int d = c & 63;
#pragma unroll
      for (int mi = 0; mi < 4; ++mi) {
#pragma unroll
        for (int r = 0; r < 4; ++r) {
          const int m = m0 + wm * 64 + mi * 16 + quad * 4 + r;
          const int b = m >> 11;
          const int t = m & (T - 1);
          const size_t bh = (size_t)(b * H + h);
          if (which == 0)
            qws[(bh * T + t) * D + d] = (bf16_t)((acc[mi][ni][r] + bval) * QSCALE);
          else
            kws[(bh * T + t) * D + d] = (bf16_t)(acc[mi][ni][r] + bval);
        }
      }
    }
  }
}

// ---------------------------------------------------------------------------
// Kernel 2: causal flash attention — round 26: P-bounce body (best measured)
// + TRIPLE-buffered K/V with depth-2 prefetch and COUNTED vmcnt barrier
// (T3/T4 mechanism; never drain vmcnt to 0 in the main loop).  Per wave a
// stage = 4 global_load_lds; at barrier of iter `it` we wait vmcnt(4)
// (stage(it) done, stage(it+1) still in flight), raw s_barrier, then issue
// stage(it+2) into buffer (it+2)%3 (disjoint from buffers read at it, it+1).
// Final iteration peeled with full __syncthreads.  LDS = 3x8KB K + 3x8KB V
// + 8KB Ph + 8KB Pl = 64 KB -> 2 blocks/CU (grid 512).
// ---------------------------------------------------------------------------
__global__ __launch_bounds__(256) void attn_kernel(
    const bf16_t* __restrict__ qws, const bf16_t* __restrict__ kws,
    const bf16_t* __restrict__ vws, bf16_t* __restrict__ yws)
{
  const int id = blockIdx.x;
  const int bh = id & 31;
  const int pr = id >> 5;            // 0..15
  const int tid  = threadIdx.x;
  const int wv   = tid >> 6;
  const int lane = tid & 63;
  const int col  = lane & 15;
  const int quad = lane >> 4;

  const bf16_t* Q  = qws + (size_t)bh * T * D;
  const bf16_t* K  = kws + (size_t)bh * T * D;
  const bf16_t* Vt = vws + (size_t)bh * D * T;

  __shared__ __align__(16) bf16_t ldsK[3][64 * 64];      // 24 KB
  __shared__ __align__(16) bf16_t ldsV[3][64 * 64];      // 24 KB
  __shared__ __align__(16) bf16_t ldsPh_s[4][16 * 64];   // 8 KB
  __shared__ __align__(16) bf16_t ldsPl_s[4][16 * 64];   // 8 KB
  bf16_t* ldsPh = ldsPh_s[wv];
  bf16_t* ldsPl = ldsPl_s[wv];

  const int xs   = col & 7;
  const int cxq  = (quad ^ xs) * 8;
  const int lr8  = lane >> 3;
  const int ksrc = (lane & 7) ^ lr8;
  const int pxor = (quad & 1) * 4;
  const int b = bh >> 4;
  const int h = bh & 15;

  const int qt_h = 31 - pr, qt_l = pr;       // qt_l < qt_h always
  const int t0h = qt_h * 64, t0l = qt_l * 64;
  const int twh = t0h + 16 * wv, twl = t0l + 16 * wv;

  bf16x8 qfh0 = *(const bf16x8*)(Q + (size_t)(twh + col) * D + quad * 8);
  bf16x8 qfh1 = *(const bf16x8*)(Q + (size_t)(twh + col) * D + 32 + quad * 8);
  bf16x8 qfl0 = *(const bf16x8*)(Q + (size_t)(twl + col) * D + quad * 8);
  bf16x8 qfl1 = *(const bf16x8*)(Q + (size_t)(twl + col) * D + 32 + quad * 8);

  f32x4 oh[4] = {}, ol[4] = {};
  f32x4 lph = {}, lpl = {};

  // stage K/V tile `it` into LDS buffer (it % 3); 4 loads per wave
  auto stage = [&](int it) {
    const int sn = it * 64;
    bf16_t* dK = ldsK[it % 3];
    bf16_t* dV = ldsV[it % 3];
#pragma unroll
    for (int j = 0; j < 2; ++j) {
      GLOAD_LDS16(K + (size_t)(sn + 16 * wv + j * 8 + lr8) * D + ksrc * 8,
                  dK + (16 * wv + j * 8) * 64);
      GLOAD_LDS16(Vt + (size_t)(16 * wv + j * 8 + lr8) * T + sn + ksrc * 8,
                  dV + (16 * wv + j * 8) * 64);
    }
  };

  // counted barrier: stage(it) complete, stage(it+1) may remain in flight
  auto cbar = [&]() {
    asm volatile("s_waitcnt vmcnt(4)" ::: "memory");
    __builtin_amdgcn_s_barrier();
  };

  // One K/V tile against hi (always) and lo (compile-time LO) q-tiles.
  // K and V fragments loaded once, fed to both tiles' MFMAs.
  auto body = [&](auto LOC, const bf16_t* bK, const bf16_t* bV,
                  int s0, bool hdiag, bool ldiag) {
    constexpr bool LO = decltype(LOC)::value;
    f32x4 sch[4], scl[4];
    __builtin_amdgcn_s_setprio(1);
#pragma unroll
    for (int kb = 0; kb < 4; ++kb) {
      const bf16_t* kr = bK + (kb * 16 + col) * 64;
      bf16x8 kf0 = *(const bf16x8*)(kr + cxq);
      bf16x8 kf1 = *(const bf16x8*)(kr + (cxq ^ 32));
      f32x4 a = {};
      a = MFMA16(qfh0, kf0, a);
      a = MFMA16(qfh1, kf1, a);
      sch[kb] = a;
      if constexpr (LO) {
        f32x4 c = {};
        c = MFMA16(qfl0, kf0, c);
        c = MFMA16(qfl1, kf1, c);
        scl[kb] = c;
      }
    }
    __builtin_amdgcn_s_setprio(0);
#pragma unroll
    for (int r = 0; r < 4; ++r) {
      const int prow = (quad * 4 + r) * 64;
      const int pxr  = pxor + r;
      const int poff = prow + (((col >> 1) ^ pxr) * 8) + (col & 1) * 4;
      bf16x4 pw;
#pragma unroll
      for (int kb = 0; kb < 4; ++kb) {
        float p = __builtin_amdgcn_exp2f(sch[kb][r]);
        if (hdiag && (s0 + kb * 16 + col > twh + quad * 4 + r)) p = 0.0f;
        lph[r] += p;
        pw[kb] = (bf16_t)p;
      }
      *(bf16x4*)(ldsPh + poff) = pw;
      if constexpr (LO) {
        bf16x4 pl;
#pragma unroll
        for (int kb = 0; kb < 4; ++kb) {
          float p = __builtin_amdgcn_exp2f(scl[kb][r]);
          if (ldiag && (s0 + kb * 16 + col > twl + quad * 4 + r)) p = 0.0f;
          lpl[r] += p;
          pl[kb] = (bf16_t)p;
        }
        *(bf16x4*)(ldsPl + poff) = pl;
      }
    }
    __builtin_amdgcn_s_setprio(1);
#pragma unroll
    for (int ks = 0; ks < 2; ++ks) {
      const int xk = cxq ^ (ks * 32);
      bf16x8 pah = *(const bf16x8*)(ldsPh + col * 64 + xk);
      bf16x8 pal{};
      if constexpr (LO) pal = *(const bf16x8*)(ldsPl + col * 64 + xk);
#pragma unroll
      for (int ni = 0; ni < 4; ++ni) {
        bf16x8 vf = *(const bf16x8*)(bV + (ni * 16 + col) * 64 + xk);
        oh[ni] = MFMA16(pah, vf, oh[ni]);
        if constexpr (LO) ol[ni] = MFMA16(pal, vf, ol[ni]);
      }
    }
    __builtin_amdgcn_s_setprio(0);
  };

  // prologue: stage tiles 0 and 1 (depth-2)
  stage(0);
  stage(1);                             // qt_h >= 16 > 1 always

  int it = 0;
  // Range A: both tiles interior
  for (; it < qt_l; ++it) {
    cbar();
    if (it + 2 <= qt_h) stage(it + 2);
    body(LoOn{}, ldsK[it % 3], ldsV[it % 3], it * 64, false, false);
  }
  // Peel it = qt_l: hi interior, lo diagonal  (qt_l < qt_h)
  {
    cbar();
    if (it + 2 <= qt_h) stage(it + 2);
    body(LoOn{}, ldsK[it % 3], ldsV[it % 3], it * 64, false, true);
    ++it;
  }
  // Range B: hi only, interior
  for (; it < qt_h; ++it) {
    cbar();
    if (it + 2 <= qt_h) stage(it + 2);
    body(LoOff{}, ldsK[it % 3], ldsV[it % 3], it * 64, false, false);
  }
  // Final it = qt_h: hi diagonal, full drain
  __syncthreads();
  body(LoOff{}, ldsK[qt_h % 3], ldsV[qt_h % 3], qt_h * 64, true, false);

  // epilogue: reduce l, normalize, write Y for both tiles
#pragma unroll
  for (int r = 0; r < 4; ++r) {
    float l0 = lph[r], l1 = lpl[r];
#pragma unroll
    for (int off = 1; off < 16; off <<= 1) {
      l0 += __shfl_xor(l0, off);
      l1 += __shfl_xor(l1, off);
    }
    const float rl0 = 1.0f / l0, rl1 = 1.0f / l1;
    const int th = twh + quad * 4 + r;
    const int tl = twl + quad * 4 + r;
#pragma unroll
    for (int ni = 0; ni < 4; ++ni) {
      const int d = ni * 16 + col;
      yws[((size_t)(b * T + th)) * C + h * D + d] = (bf16_t)(oh[ni][r] * rl0);
      yws[((size_t)(b * T + tl)) * C + h * D + d] = (bf16_t)(ol[ni][r] * rl1);
    }
  }
}

// ---------------------------------------------------------------------------
// Kernel 3: output projection — 128x64 dbuf (48 KB LDS, 512 blocks = 3/CU,
// 16 MFMA/wave/iter), f32 output.
// ---------------------------------------------------------------------------
__global__ __launch_bounds__(256) void proj_gemm_kernel(
    const bf16_t* __restrict__ y, const bf16_t* __restrict__ w,
    const float* __restrict__ bias, float* __restrict__ out)
{
  __shared__ __align__(16) bf16_t ldsA[2][128 * 64];
  __shared__ __align__(16) bf16_t ldsB[2][64 * 64];
  const int lane = threadIdx.x & 63;
  const int wv   = threadIdx.x >> 6;
  const int col  = lane & 15;
  const int quad = lane >> 4;
  const int wm = wv >> 1, wn = wv & 1;
  const int m0 = blockIdx.y * 128;
  const int n0 = blockIdx.x * 64;

  f32x4 acc[4][2] = {};
  gemm_mainloop_db<128, 64, 4, 2>(y, w, C, m0, n0,
                                  ldsA[0], ldsA[1], ldsB[0], ldsB[1], acc);

#pragma unroll
  for (int ni = 0; ni < 2; ++ni) {
    const int n = n0 + wn * 32 + ni * 16 + col;
    const float bval = bias[n];
#pragma unroll
    for (int mi = 0; mi < 4; ++mi) {
#pragma unroll
      for (int r = 0; r < 4; ++r) {
        const int m = m0 + wm * 64 + mi * 16 + quad * 4 + r;
        out[(size_t)m * C + n] = acc[mi][ni][r] + bval;
      }
    }
  }
}

// ---------------------------------------------------------------------------
extern "C" void kernel_launch(void* const* d_in, const int* in_sizes, int n_in,
                              void* d_out, int out_size, void* d_ws, size_t ws_size,
                              hipStream_t stream) {
  const float* x      = (const float*)d_in[0];
  const float* attn_w = (const float*)d_in[1];
  const float* attn_b = (const float*)d_in[2];
  const float* proj_w = (const float*)d_in[3];
  const float* proj_b = (const float*)d_in[4];
  float* out = (float*)d_out;

  const size_t E = (size_t)B * H * T * D;   // 4,194,304
  char* ws = (char*)d_ws;
  bf16_t* qws = (bf16_t*)(ws);
  bf16_t* kws = (bf16_t*)(ws + 2 * E);
  bf16_t* vws = (bf16_t*)(ws + 4 * E);
  bf16_t* yws = (bf16_t*)(ws + 6 * E);
  bf16_t* xb  = (bf16_t*)(ws + 8 * E);
  bf16_t* awb = (bf16_t*)(ws + 10 * E);
  bf16_t* pwb = (bf16_t*)(ws + 11 * E + E / 2);

  cvt_kernel<<<4096, 256, 0, stream>>>(x, xb, attn_w, awb, proj_w, pwb);
  qkv_gemm_kernel<<<dim3(NQKV / 128, M / 128), 256, 0, stream>>>(
      xb, awb, attn_b, qws, kws, vws);
  attn_kernel<<<512, 256, 0, stream>>>(qws, kws, vws, yws);
  proj_gemm_kernel<<<dim3(C / 64, M / 128), 256, 0, stream>>>(
      yws, pwb, proj_b, out);
}